// Round 7
// baseline (69.588 us; speedup 1.0000x reference)
//
#include <hip/hip_runtime.h>
#include <hip/hip_bf16.h>

#define N_ATOMS   200000
#define D_IN      256
#define D_OUT     256
#define N_SPECIES 4
#define N_STRUCT  2000
#define M_PAD     2048      // padded struct rows for GEMM tiling
#define KFLAT     1024      // N_SPECIES * D_IN
#define SEG_D     16        // LDS ring slots per wave

typedef __attribute__((ext_vector_type(8))) short bf16x8;
typedef __attribute__((ext_vector_type(4))) float f32x4;

typedef const __attribute__((address_space(1))) float gfloat;
typedef __attribute__((address_space(3))) float lfloat;

__device__ inline unsigned short f2bf(float f) {
    unsigned int u = __float_as_uint(f);
    unsigned int r = (u + 0x7fffu + ((u >> 16) & 1u)) >> 16;   // RNE
    return (unsigned short)r;
}

// ---- ws layout (bytes) ----
// 0        : Wt  bf16 [16][256][64]   = 524288   (kbg = s*4 + (k>>6), [n][k'] per block)
// 524288   : S   bf16 [2048][1024]    = 4194304  (rows >= 2000 stay poison, never stored)
// 4718592  : cnt f32  [2048][4]       = 32768

// K1: write-coalesced W transpose/convert. Thread owns 4 consecutive output
// bf16 (8B store); the transpose scatter goes to the READ side (4x4B strided,
// L2-absorbed, massive TLP).
__global__ void k_wt2(const float* __restrict__ W, unsigned short* __restrict__ Wt) {
    int gid = blockIdx.x * 256 + threadIdx.x;   // 131072 threads
    int o   = gid * 4;                          // flat output index (shorts)
    int kbg = o >> 14;
    int nn  = (o >> 6) & 255;
    int kp  = o & 63;
    int s   = kbg >> 2, kb = kbg & 3;
    int k0  = kb * 64 + kp;
    const float* wb = W + (size_t)s * 65536 + (size_t)k0 * 256 + nn;
    ushort4 u;
    u.x = f2bf(wb[0]);
    u.y = f2bf(wb[256]);
    u.z = f2bf(wb[512]);
    u.w = f2bf(wb[768]);
    *(ushort4*)(Wt + o) = u;
}

// 64-ary lower_bound over sorted sidx (whole wave participates)
__device__ __forceinline__ int lb64(const int* __restrict__ sidx, int key, int lane) {
    int lo = 0, hi = N_ATOMS;
    while (hi - lo > 64) {
        int step = (hi - lo + 63) >> 6;
        int pos  = lo + lane * step;
        int v    = (pos < hi) ? sidx[pos] : 0x7fffffff;
        unsigned long long m = __ballot(v < key);
        int c = __popcll(m);
        int nlo = (c == 0)  ? lo : (lo + (c - 1) * step + 1);
        int nhi = (c == 64) ? hi : min(hi, lo + c * step);
        lo = nlo; hi = nhi;
    }
    int pos = lo + lane;
    int v   = (pos < hi) ? sidx[pos] : 0x7fffffff;
    unsigned long long m = __ballot(v < key);
    return lo + __popcll(m);
}

// K2: ONE WAVE = ONE STRUCTURE. Hardware-queued depth-15 pipeline:
// global_load_lds into a wave-private 16-slot LDS ring, counted vmcnt(14)
// waits. Species handled via per-64-row ballot masks (pure SALU in hot loop,
// zero vmem ops besides the x-row loads -> exact vmcnt bookkeeping).
__global__ __launch_bounds__(256) void k_seg4(
        const float* __restrict__ x, const int* __restrict__ spec,
        const int* __restrict__ sidx, unsigned short* __restrict__ S,
        float* __restrict__ cnt) {

    __shared__ __align__(16) float ring[4][SEG_D][256];   // 64 KB

    int t = threadIdx.x, w = t >> 6, lane = t & 63;
    int g = blockIdx.x * 4 + w;
    if (g >= N_STRUCT) return;

    int s0 = lb64(sidx, g,     lane);
    int s1 = lb64(sidx, g + 1, lane);
    int n  = s1 - s0;

    f32x4 a0 = (f32x4){0.f,0.f,0.f,0.f}, a1 = a0, a2 = a0, a3 = a0;
    float c0 = 0.f, c1 = 0.f, c2 = 0.f, c3 = 0.f;

    if (n > 0) {
        int nm1 = n - 1;
        const float* gp0 = x + (size_t)s0 * 256 + lane * 4;   // per-lane base

        // drain lb64's vector loads so vmcnt counts only ring loads
        asm volatile("s_waitcnt vmcnt(0)" ::: "memory");

        // prime rows 0..14
#pragma unroll
        for (int j = 0; j < 15; ++j) {
            int rr = min(j, nm1);
            __builtin_amdgcn_global_load_lds(
                (gfloat*)(gp0 + (size_t)rr * 256),
                (lfloat*)&ring[w][j & (SEG_D - 1)][0], 16, 0, 0);
        }

        for (int cb = 0; cb < n; cb += 64) {
            // coalesced spec chunk load + drain (once per 64 rows)
            int spv = spec[s0 + min(cb + lane, nm1)];
            asm volatile("s_waitcnt vmcnt(0)" ::: "memory");
            unsigned long long m0 = __ballot((spv & 1) != 0);
            unsigned long long m1 = __ballot((spv & 2) != 0);

            int ce = min(n, cb + 64);
            for (int j = cb; j < ce; ++j) {
                asm volatile("s_waitcnt vmcnt(14)" ::: "memory");
                f32x4 v = *(const f32x4*)&ring[w][j & (SEG_D - 1)][lane * 4];
                int r  = j - cb;
                int sp = (int)((m0 >> r) & 1ull) | ((int)((m1 >> r) & 1ull) << 1);
                switch (sp) {
                    case 0: a0 += v; c0 += 1.f; break;
                    case 1: a1 += v; c1 += 1.f; break;
                    case 2: a2 += v; c2 += 1.f; break;
                    default: a3 += v; c3 += 1.f; break;
                }
                int rr = min(j + 15, nm1);
                __builtin_amdgcn_global_load_lds(
                    (gfloat*)(gp0 + (size_t)rr * 256),
                    (lfloat*)&ring[w][(j + 15) & (SEG_D - 1)][0], 16, 0, 0);
            }
        }
    }

    unsigned short* Sg = S + (size_t)g * KFLAT + lane * 4;
    ushort4 u;
    u.x = f2bf(a0[0]); u.y = f2bf(a0[1]); u.z = f2bf(a0[2]); u.w = f2bf(a0[3]);
    *(ushort4*)(Sg + 0)   = u;
    u.x = f2bf(a1[0]); u.y = f2bf(a1[1]); u.z = f2bf(a1[2]); u.w = f2bf(a1[3]);
    *(ushort4*)(Sg + 256) = u;
    u.x = f2bf(a2[0]); u.y = f2bf(a2[1]); u.z = f2bf(a2[2]); u.w = f2bf(a2[3]);
    *(ushort4*)(Sg + 512) = u;
    u.x = f2bf(a3[0]); u.y = f2bf(a3[1]); u.z = f2bf(a3[2]); u.w = f2bf(a3[3]);
    *(ushort4*)(Sg + 768) = u;

    if (lane == 0) {
        float4 c4; c4.x = c0; c4.y = c1; c4.z = c2; c4.w = c3;
        *(float4*)(cnt + (size_t)g * 4) = c4;
    }
}

// K3: barrier-free GEMM. 128 blocks x 4 waves; each wave owns a 16x64 tile,
// A-frags direct from S (L2/L3), B-frags direct from Wt (L2). No LDS.
__global__ __launch_bounds__(256) void k_gemm3(
        const unsigned short* __restrict__ S, const float* __restrict__ cnt,
        const float* __restrict__ b, const unsigned short* __restrict__ Wt,
        float* __restrict__ out) {

    int t = threadIdx.x, nt = t >> 6, lane = t & 63;
    int l15 = lane & 15, l4 = lane >> 4;
    int g0 = blockIdx.x * 16;

    f32x4 acc[4];
#pragma unroll
    for (int n = 0; n < 4; ++n) acc[n] = (f32x4){0.f, 0.f, 0.f, 0.f};

    const unsigned short* arow = S + (size_t)(g0 + l15) * KFLAT + l4 * 8;

#pragma unroll 4
    for (int kbg = 0; kbg < 16; ++kbg) {
        const unsigned short* wkb = Wt + (size_t)kbg * 16384 + l4 * 8;
#pragma unroll
        for (int ks = 0; ks < 2; ++ks) {
            bf16x8 af = *(const bf16x8*)(arow + kbg * 64 + ks * 32);
#pragma unroll
            for (int n = 0; n < 4; ++n) {
                bf16x8 bfr = *(const bf16x8*)(wkb + (size_t)(nt * 64 + n * 16 + l15) * 64 + ks * 32);
                acc[n] = __builtin_amdgcn_mfma_f32_16x16x32_bf16(af, bfr, acc[n], 0, 0, 0);
            }
        }
    }

    float bv[4][4];
#pragma unroll
    for (int n = 0; n < 4; ++n) {
        int col = nt * 64 + n * 16 + l15;
#pragma unroll
        for (int s = 0; s < 4; ++s) bv[n][s] = b[s * 256 + col];
    }

#pragma unroll
    for (int r = 0; r < 4; ++r) {
        int grow = g0 + l4 * 4 + r;
        if (grow < N_STRUCT) {
            float4 c4 = *(const float4*)(cnt + (size_t)grow * 4);
#pragma unroll
            for (int n = 0; n < 4; ++n) {
                int col = nt * 64 + n * 16 + l15;
                out[(size_t)grow * 256 + col] =
                    acc[n][r] + c4.x * bv[n][0] + c4.y * bv[n][1]
                              + c4.z * bv[n][2] + c4.w * bv[n][3];
            }
        }
    }
}

extern "C" void kernel_launch(void* const* d_in, const int* in_sizes, int n_in,
                              void* d_out, int out_size, void* d_ws, size_t ws_size,
                              hipStream_t stream) {
    const float* x    = (const float*)d_in[0];
    const float* W    = (const float*)d_in[1];
    const float* b    = (const float*)d_in[2];
    const int* spec   = (const int*)d_in[3];
    const int* sidx   = (const int*)d_in[4];
    float* out        = (float*)d_out;

    char* ws = (char*)d_ws;
    unsigned short* Wt = (unsigned short*)ws;               // 524288 B
    unsigned short* S  = (unsigned short*)(ws + 524288);    // 4194304 B
    float* cnt  = (float*)(ws + 4718592);                   // 32768 B

    k_wt2  <<<512, 256, 0, stream>>>(W, Wt);
    k_seg4 <<<(N_STRUCT + 3) / 4, 256, 0, stream>>>(x, spec, sidx, S, cnt);
    k_gemm3<<<M_PAD / 16, 256, 0, stream>>>(S, cnt, b, Wt, out);
}